// Round 2
// baseline (947.312 us; speedup 1.0000x reference)
//
#include <hip/hip_runtime.h>

#define B_   64
#define L_   2048
#define H_   256
#define E_   256
#define V_   50257
#define TWOH 512
#define VL   52305   // V_ + L_

typedef short bf16x8 __attribute__((ext_vector_type(8)));
typedef float f32x4  __attribute__((ext_vector_type(4)));

__device__ inline unsigned short f2bf(float f){
  unsigned u = __float_as_uint(f);
  unsigned r = (u + 0x7fffu + ((u >> 16) & 1u)) >> 16;  // RNE
  return (unsigned short)r;
}
__device__ inline float fast_tanh(float x){
  x = fminf(15.f, fmaxf(-15.f, x));
  float e = __expf(2.f * x);
  return (e - 1.f) / (e + 1.f);
}
__device__ inline float fast_sigmoid(float x){
  return 1.f / (1.f + __expf(-x));
}

// K0: WcT[n][k] = bf16(Wc[k][n]);  Wc is (512,256) row-major.
__global__ __launch_bounds__(256) void k_prep(const float* __restrict__ Wc,
                                              unsigned short* __restrict__ WcT){
  int i = blockIdx.x * 256 + threadIdx.x;       // 131072 total
  int n = i >> 9, k = i & 511;
  WcT[i] = f2bf(Wc[(size_t)k * 256 + n]);
}

// K1: attn_in = [emb, pre_state]; zero applied; cnt[b] = #matches
__global__ __launch_bounds__(256) void k_setup(const int* __restrict__ idx, const int* __restrict__ seq,
    const float* __restrict__ embed, const float* __restrict__ pre_state,
    float* __restrict__ attn_in, float* __restrict__ applied, float* __restrict__ cnt){
  int b = blockIdx.x, t = threadIdx.x;
  int id = idx[b];
  attn_in[b * 512 + t]       = embed[(size_t)id * 256 + t];
  attn_in[b * 512 + 256 + t] = pre_state[b * 256 + t];
  applied[b * 512 + t] = 0.f;
  applied[b * 512 + 256 + t] = 0.f;
  int c = 0;
  for (int l = t; l < 2048; l += 256) c += (seq[b * 2048 + l] == id) ? 1 : 0;
  __shared__ int red[256];
  red[t] = c; __syncthreads();
  for (int o = 128; o; o >>= 1){ if (t < o) red[t] += red[t + o]; __syncthreads(); }
  if (t == 0) cnt[b] = (float)red[0];
}

// K2: logits[b,l] = attn_in[b,:] . attn_W[:,l] + attn_b[l]
__global__ __launch_bounds__(256) void k_logits(const float* __restrict__ attn_in,
    const float* __restrict__ attn_W, const float* __restrict__ attn_b, float* __restrict__ logits){
  int lt = blockIdx.x, b = blockIdx.y, t = threadIdx.x;
  int l = lt * 256 + t;
  __shared__ float ai[512];
  ai[t] = attn_in[b * 512 + t];
  ai[256 + t] = attn_in[b * 512 + 256 + t];
  __syncthreads();
  float acc = attn_b[l];
  for (int k4 = 0; k4 < 128; ++k4){
    const float4 a = *(const float4*)&ai[k4 * 4];
    acc += a.x * attn_W[(size_t)(k4 * 4 + 0) * 2048 + l]
         + a.y * attn_W[(size_t)(k4 * 4 + 1) * 2048 + l]
         + a.z * attn_W[(size_t)(k4 * 4 + 2) * 2048 + l]
         + a.w * attn_W[(size_t)(k4 * 4 + 3) * 2048 + l];
  }
  logits[b * 2048 + l] = acc;
}

// K2b: w[b,l] = softmax_l(logits) + match/max(cnt,1)*pre_prob_c
__global__ __launch_bounds__(256) void k_weights(const float* __restrict__ logits,
    const int* __restrict__ seq, const int* __restrict__ idx, const float* __restrict__ ppc,
    const float* __restrict__ cnt, float* __restrict__ w){
  int b = blockIdx.x, t = threadIdx.x;
  float v[8];
  float m = -3e38f;
#pragma unroll
  for (int i = 0; i < 8; ++i){ v[i] = logits[b * 2048 + i * 256 + t]; m = fmaxf(m, v[i]); }
  __shared__ float red[256];
  red[t] = m; __syncthreads();
  for (int o = 128; o; o >>= 1){ if (t < o) red[t] = fmaxf(red[t], red[t + o]); __syncthreads(); }
  m = red[0]; __syncthreads();
  float s = 0.f;
#pragma unroll
  for (int i = 0; i < 8; ++i){ v[i] = __expf(v[i] - m); s += v[i]; }
  red[t] = s; __syncthreads();
  for (int o = 128; o; o >>= 1){ if (t < o) red[t] += red[t + o]; __syncthreads(); }
  float invZ = 1.f / red[0];
  int id = idx[b];
  float invc = 1.f / fmaxf(cnt[b], 1.f);
#pragma unroll
  for (int i = 0; i < 8; ++i){
    int l = i * 256 + t;
    float sw = (seq[b * 2048 + l] == id) ? ppc[b * 2048 + l] * invc : 0.f;
    w[b * 2048 + l] = v[i] * invZ + sw;
  }
}

// K3: applied[b,d] = sum_l w[b,l]*enc[b,l,d]   (268 MB pass, atomics over 8 l-chunks)
__global__ __launch_bounds__(256) void k_applied(const float* __restrict__ enc,
    const float* __restrict__ w, float* __restrict__ applied){
  int lc = blockIdx.x, b = blockIdx.y, t = threadIdx.x;
  __shared__ float sw[256];
  sw[t] = w[b * 2048 + lc * 256 + t];
  __syncthreads();
  float ax = 0.f, ay = 0.f;
  for (int l = 0; l < 256; ++l){
    const float2 v = *(const float2*)(enc + ((size_t)b * 2048 + lc * 256 + l) * 512 + 2 * t);
    float wl = sw[l];
    ax += wl * v.x; ay += wl * v.y;
  }
  atomicAdd(&applied[b * 512 + 2 * t],     ax);
  atomicAdd(&applied[b * 512 + 2 * t + 1], ay);
}

// K4: GRU -> state (also writes state output)
__global__ __launch_bounds__(256) void k_gru(const float* __restrict__ attn_in,
    const float* __restrict__ applied, const float* __restrict__ Wih, const float* __restrict__ Whh,
    const float* __restrict__ bih, const float* __restrict__ bhh,
    float* __restrict__ state, float* __restrict__ out_state){
  int b = blockIdx.x, t = threadIdx.x;
  __shared__ float xs[768];
  __shared__ float ps[256];
  xs[t] = attn_in[b * 512 + t];                 // emb
  ps[t] = attn_in[b * 512 + 256 + t];           // pre_state
  xs[256 + t] = applied[b * 512 + t];
  xs[512 + t] = applied[b * 512 + 256 + t];
  __syncthreads();
  float gi[3], gh[3];
#pragma unroll
  for (int g = 0; g < 3; ++g){
    const float4* wr = (const float4*)(Wih + (size_t)(g * 256 + t) * 768);
    float a = bih[g * 256 + t];
    for (int k = 0; k < 192; ++k){
      float4 wv = wr[k];
      const float4 xv = *(const float4*)&xs[k * 4];
      a += wv.x * xv.x + wv.y * xv.y + wv.z * xv.z + wv.w * xv.w;
    }
    gi[g] = a;
    const float4* hr = (const float4*)(Whh + (size_t)(g * 256 + t) * 256);
    float c = bhh[g * 256 + t];
    for (int k = 0; k < 64; ++k){
      float4 wv = hr[k];
      const float4 xv = *(const float4*)&ps[k * 4];
      c += wv.x * xv.x + wv.y * xv.y + wv.z * xv.z + wv.w * xv.w;
    }
    gh[g] = c;
  }
  float r = fast_sigmoid(gi[0] + gh[0]);
  float z = fast_sigmoid(gi[1] + gh[1]);
  float n = fast_tanh(gi[2] + r * gh[2]);
  float st = (1.f - z) * n + z * ps[t];
  state[b * 256 + t] = st;
  out_state[b * 256 + t] = st;
}

// K6: score_g (into out1, temporarily) = state @ Wo + Wo_b, via bf16 MFMA.
// Block: one 256-wide v-tile, all 64 b rows. 4 waves x 16 n-frags.
__global__ __launch_bounds__(256) void k_scoreg(const float* __restrict__ Wo,
    const float* __restrict__ Wob, const float* __restrict__ state, float* __restrict__ out1){
  int v0 = blockIdx.x * 256;
  int tid = threadIdx.x;
  int wave = tid >> 6, lane = tid & 63;
  int lr = lane & 15, q = lane >> 4;
  __shared__ unsigned short sA[64 * 264];   // state bf16, row stride 264 (pad: 2-way banks)
  __shared__ unsigned short sB[256 * 40];   // WoT slice [n][k'] stride 40
  for (int i = tid; i < 64 * 256; i += 256){
    int r = i >> 8, c = i & 255;
    sA[r * 264 + c] = f2bf(state[i]);
  }
  f32x4 zero = {0.f, 0.f, 0.f, 0.f};
  f32x4 acc[16];
#pragma unroll
  for (int i = 0; i < 16; ++i) acc[i] = zero;
  int v = v0 + tid;
  for (int kk = 0; kk < 8; ++kk){
    __syncthreads();
    for (int r = 0; r < 32; ++r){
      float val = (v < V_) ? Wo[(size_t)(kk * 32 + r) * V_ + v] : 0.f;
      sB[tid * 40 + r] = f2bf(val);
    }
    __syncthreads();
    bf16x8 af = *(const bf16x8*)&sA[(wave * 16 + lr) * 264 + kk * 32 + q * 8];
#pragma unroll
    for (int nf = 0; nf < 16; ++nf){
      bf16x8 bf = *(const bf16x8*)&sB[(nf * 16 + lr) * 40 + q * 8];
      acc[nf] = __builtin_amdgcn_mfma_f32_16x16x32_bf16(af, bf, acc[nf], 0, 0, 0);
    }
  }
#pragma unroll
  for (int nf = 0; nf < 16; ++nf){
    int vv = v0 + nf * 16 + lr;
    if (vv < V_){
      float wb = Wob[vv];
#pragma unroll
      for (int r = 0; r < 4; ++r){
        int bb = wave * 16 + q * 4 + r;
        out1[(size_t)bb * VL + vv] = acc[nf][r] + wb;
      }
    }
  }
}

// K5: score_c[b,l] = sum_h tanh((enc@Wc)[b,l,h] + Wcb[h]) * state[b,h]
// Block: (b, 64-row l-tile). 4 waves x 16 rows each; K=512 staged in 16 slices.
__global__ __launch_bounds__(256) void k_scorec(const float* __restrict__ enc,
    const unsigned short* __restrict__ WcT, const float* __restrict__ Wcb,
    const float* __restrict__ state, float* __restrict__ score_c){
  int lt = blockIdx.x, b = blockIdx.y;
  int tid = threadIdx.x;
  int wave = tid >> 6, lane = tid & 63;
  int lr = lane & 15, q = lane >> 4;
  __shared__ unsigned short s_wc[256 * 40];  // [col][k'] stride 40 (pad: 2-way banks)
  __shared__ float s_state[256];
  __shared__ float s_bias[256];
  s_state[tid] = state[b * 256 + tid];
  s_bias[tid]  = Wcb[tid];
  f32x4 zero = {0.f, 0.f, 0.f, 0.f};
  f32x4 acc[16];
#pragma unroll
  for (int i = 0; i < 16; ++i) acc[i] = zero;
  const float* arow = enc + ((size_t)b * 2048 + lt * 64 + wave * 16 + lr) * 512;
  for (int kk = 0; kk < 16; ++kk){
    {
      const uint4* src = (const uint4*)(WcT + (size_t)tid * 512 + kk * 32);
      uint4* dst = (uint4*)&s_wc[tid * 40];
      dst[0] = src[0]; dst[1] = src[1]; dst[2] = src[2]; dst[3] = src[3];
    }
    __syncthreads();
    float4 a0 = *(const float4*)(arow + kk * 32 + q * 8);
    float4 a1 = *(const float4*)(arow + kk * 32 + q * 8 + 4);
    bf16x8 af;
    af[0] = f2bf(a0.x); af[1] = f2bf(a0.y); af[2] = f2bf(a0.z); af[3] = f2bf(a0.w);
    af[4] = f2bf(a1.x); af[5] = f2bf(a1.y); af[6] = f2bf(a1.z); af[7] = f2bf(a1.w);
#pragma unroll
    for (int nf = 0; nf < 16; ++nf){
      bf16x8 bf = *(const bf16x8*)&s_wc[(nf * 16 + lr) * 40 + q * 8];
      acc[nf] = __builtin_amdgcn_mfma_f32_16x16x32_bf16(af, bf, acc[nf], 0, 0, 0);
    }
    __syncthreads();
  }
  float part[4] = {0.f, 0.f, 0.f, 0.f};
#pragma unroll
  for (int nf = 0; nf < 16; ++nf){
    int col = nf * 16 + lr;
    float sv = s_state[col], bv = s_bias[col];
#pragma unroll
    for (int r = 0; r < 4; ++r){
      part[r] += fast_tanh(acc[nf][r] + bv) * sv;
    }
  }
#pragma unroll
  for (int m = 1; m <= 8; m <<= 1){
#pragma unroll
    for (int r = 0; r < 4; ++r) part[r] += __shfl_xor(part[r], m, 64);
  }
  if (lr == 0){
#pragma unroll
    for (int r = 0; r < 4; ++r)
      score_c[b * 2048 + lt * 64 + wave * 16 + q * 4 + r] = part[r];
  }
}

// K7: per-b online softmax stats over [score_g (in out1), score_c]
__global__ __launch_bounds__(256) void k_stats(const float* __restrict__ out1,
    const float* __restrict__ score_c, float* __restrict__ mz){
  int b = blockIdx.x, t = threadIdx.x;
  float m = -3.0e38f, s = 0.f;
  const float* sg = out1 + (size_t)b * VL;
  for (int i = t; i < V_; i += 256){
    float v = sg[i];
    if (v > m){ s = s * __expf(m - v) + 1.f; m = v; }
    else s += __expf(v - m);
  }
  const float* sc = score_c + b * 2048;
  for (int i = t; i < 2048; i += 256){
    float v = sc[i];
    if (v > m){ s = s * __expf(m - v) + 1.f; m = v; }
    else s += __expf(v - m);
  }
  __shared__ float ms[256], ss[256];
  ms[t] = m; ss[t] = s; __syncthreads();
  for (int o = 128; o; o >>= 1){
    if (t < o){
      float m2 = ms[t + o], s2 = ss[t + o];
      float mn = fmaxf(ms[t], m2);
      ss[t] = ss[t] * __expf(ms[t] - mn) + s2 * __expf(m2 - mn);
      ms[t] = mn;
    }
    __syncthreads();
  }
  if (t == 0){ mz[2 * b] = ms[0]; mz[2 * b + 1] = ss[0]; }
}

// K8a: in-place out1[b,i] = i<V ? exp(sg-m)/Z : 0
__global__ __launch_bounds__(256) void k_probg(float* __restrict__ out1, const float* __restrict__ mz){
  int b = blockIdx.y;
  int i = blockIdx.x * 256 + threadIdx.x;
  if (i >= VL) return;
  float m = mz[2 * b], z = mz[2 * b + 1];
  float* row = out1 + (size_t)b * VL;
  row[i] = (i < V_) ? __expf(row[i] - m) / z : 0.f;
}

// K8b: prob_c out + scatter-add into out1 first-V columns
__global__ __launch_bounds__(256) void k_probc(const float* __restrict__ score_c,
    const float* __restrict__ mz, const int* __restrict__ seq,
    float* __restrict__ out1, float* __restrict__ out3){
  int b = blockIdx.y;
  int l = blockIdx.x * 256 + threadIdx.x;
  float m = mz[2 * b], z = mz[2 * b + 1];
  float p = __expf(score_c[b * 2048 + l] - m) / z;
  out3[b * 2048 + l] = p;
  atomicAdd(&out1[(size_t)b * VL + seq[b * 2048 + l]], p);
}

extern "C" void kernel_launch(void* const* d_in, const int* in_sizes, int n_in,
                              void* d_out, int out_size, void* d_ws, size_t ws_size,
                              hipStream_t stream) {
  const int*   idx      = (const int*)d_in[0];
  const float* enc      = (const float*)d_in[1];
  const int*   seq      = (const int*)d_in[2];
  const float* prestate = (const float*)d_in[3];
  const float* ppc      = (const float*)d_in[4];
  const float* embed    = (const float*)d_in[5];
  const float* attn_W   = (const float*)d_in[6];
  const float* attn_b   = (const float*)d_in[7];
  const float* Wih      = (const float*)d_in[8];
  const float* Whh      = (const float*)d_in[9];
  const float* bih      = (const float*)d_in[10];
  const float* bhh      = (const float*)d_in[11];
  const float* Wc       = (const float*)d_in[12];
  const float* Wcb      = (const float*)d_in[13];
  const float* Wo       = (const float*)d_in[14];
  const float* Wob      = (const float*)d_in[15];

  float* out1 = (float*)d_out;                       // (B, V+L)
  float* out2 = out1 + (size_t)B_ * VL;              // state (B,H)
  float* out3 = out2 + (size_t)B_ * H_;              // prob_c (B,L)

  char* w8 = (char*)d_ws;
  unsigned short* WcT = (unsigned short*)(w8 + 0);        // 262144 B
  float* attn_in = (float*)(w8 + 262144);                  // 131072 B
  float* logits  = (float*)(w8 + 393216);                  // 524288 B
  float* wgt     = (float*)(w8 + 917504);                  // 524288 B
  float* applied = (float*)(w8 + 1441792);                 // 131072 B
  float* state   = (float*)(w8 + 1572864);                 // 65536 B
  float* score_c = (float*)(w8 + 1638400);                 // 524288 B
  float* mz      = (float*)(w8 + 2162688);                 // 512 B
  float* cnt     = (float*)(w8 + 2163200);                 // 256 B

  k_prep   <<<512, 256, 0, stream>>>(Wc, WcT);
  k_setup  <<<64, 256, 0, stream>>>(idx, seq, embed, prestate, attn_in, applied, cnt);
  k_logits <<<dim3(8, 64), 256, 0, stream>>>(attn_in, attn_W, attn_b, logits);
  k_weights<<<64, 256, 0, stream>>>(logits, seq, idx, ppc, cnt, wgt);
  k_applied<<<dim3(8, 64), 256, 0, stream>>>(enc, wgt, applied);
  k_gru    <<<64, 256, 0, stream>>>(attn_in, applied, Wih, Whh, bih, bhh, state, out2);
  k_scoreg <<<197, 256, 0, stream>>>(Wo, Wob, state, out1);
  k_scorec <<<dim3(32, 64), 256, 0, stream>>>(enc, WcT, Wcb, state, score_c);
  k_stats  <<<64, 256, 0, stream>>>(out1, score_c, mz);
  k_probg  <<<dim3(205, 64), 256, 0, stream>>>(out1, mz);
  k_probc  <<<dim3(8, 64), 256, 0, stream>>>(score_c, mz, seq, out1, out3);
}

// Round 3
// 735.294 us; speedup vs baseline: 1.2883x; 1.2883x over previous
//
#include <hip/hip_runtime.h>

#define B_   64
#define L_   2048
#define H_   256
#define E_   256
#define V_   50257
#define TWOH 512
#define VL   52305   // V_ + L_

typedef short bf16x8 __attribute__((ext_vector_type(8)));
typedef float f32x4  __attribute__((ext_vector_type(4)));

__device__ inline unsigned short f2bf(float f){
  unsigned u = __float_as_uint(f);
  unsigned r = (u + 0x7fffu + ((u >> 16) & 1u)) >> 16;  // RNE
  return (unsigned short)r;
}
__device__ inline float fast_tanh(float x){
  x = fminf(15.f, fmaxf(-15.f, x));
  float e = __expf(2.f * x);
  return (e - 1.f) / (e + 1.f);
}
__device__ inline float fast_sigmoid(float x){
  return 1.f / (1.f + __expf(-x));
}

// K0: WcT[n][k] = bf16(Wc[k][n]);  Wc is (512,256) row-major.
__global__ __launch_bounds__(256) void k_prep(const float* __restrict__ Wc,
                                              unsigned short* __restrict__ WcT){
  int i = blockIdx.x * 256 + threadIdx.x;       // 131072 total
  int n = i >> 9, k = i & 511;
  WcT[i] = f2bf(Wc[(size_t)k * 256 + n]);
}

// K1: attn_in = [emb, pre_state]; zero applied; cnt[b] = #matches
__global__ __launch_bounds__(256) void k_setup(const int* __restrict__ idx, const int* __restrict__ seq,
    const float* __restrict__ embed, const float* __restrict__ pre_state,
    float* __restrict__ attn_in, float* __restrict__ applied, float* __restrict__ cnt){
  int b = blockIdx.x, t = threadIdx.x;
  int id = idx[b];
  attn_in[b * 512 + t]       = embed[(size_t)id * 256 + t];
  attn_in[b * 512 + 256 + t] = pre_state[b * 256 + t];
  applied[b * 512 + t] = 0.f;
  applied[b * 512 + 256 + t] = 0.f;
  int c = 0;
  for (int l = t; l < 2048; l += 256) c += (seq[b * 2048 + l] == id) ? 1 : 0;
  __shared__ int red[256];
  red[t] = c; __syncthreads();
  for (int o = 128; o; o >>= 1){ if (t < o) red[t] += red[t + o]; __syncthreads(); }
  if (t == 0) cnt[b] = (float)red[0];
}

// K2: logits[b,l] = attn_in[b,:] . attn_W[:,l] + attn_b[l]
__global__ __launch_bounds__(256) void k_logits(const float* __restrict__ attn_in,
    const float* __restrict__ attn_W, const float* __restrict__ attn_b, float* __restrict__ logits){
  int lt = blockIdx.x, b = blockIdx.y, t = threadIdx.x;
  int l = lt * 256 + t;
  __shared__ float ai[512];
  ai[t] = attn_in[b * 512 + t];
  ai[256 + t] = attn_in[b * 512 + 256 + t];
  __syncthreads();
  float acc = attn_b[l];
  for (int k4 = 0; k4 < 128; ++k4){
    const float4 a = *(const float4*)&ai[k4 * 4];
    acc += a.x * attn_W[(size_t)(k4 * 4 + 0) * 2048 + l]
         + a.y * attn_W[(size_t)(k4 * 4 + 1) * 2048 + l]
         + a.z * attn_W[(size_t)(k4 * 4 + 2) * 2048 + l]
         + a.w * attn_W[(size_t)(k4 * 4 + 3) * 2048 + l];
  }
  logits[b * 2048 + l] = acc;
}

// K2b: w[b,l] = softmax_l(logits) + match/max(cnt,1)*pre_prob_c
__global__ __launch_bounds__(256) void k_weights(const float* __restrict__ logits,
    const int* __restrict__ seq, const int* __restrict__ idx, const float* __restrict__ ppc,
    const float* __restrict__ cnt, float* __restrict__ w){
  int b = blockIdx.x, t = threadIdx.x;
  float v[8];
  float m = -3e38f;
#pragma unroll
  for (int i = 0; i < 8; ++i){ v[i] = logits[b * 2048 + i * 256 + t]; m = fmaxf(m, v[i]); }
  __shared__ float red[256];
  red[t] = m; __syncthreads();
  for (int o = 128; o; o >>= 1){ if (t < o) red[t] = fmaxf(red[t], red[t + o]); __syncthreads(); }
  m = red[0]; __syncthreads();
  float s = 0.f;
#pragma unroll
  for (int i = 0; i < 8; ++i){ v[i] = __expf(v[i] - m); s += v[i]; }
  red[t] = s; __syncthreads();
  for (int o = 128; o; o >>= 1){ if (t < o) red[t] += red[t + o]; __syncthreads(); }
  float invZ = 1.f / red[0];
  int id = idx[b];
  float invc = 1.f / fmaxf(cnt[b], 1.f);
#pragma unroll
  for (int i = 0; i < 8; ++i){
    int l = i * 256 + t;
    float sw = (seq[b * 2048 + l] == id) ? ppc[b * 2048 + l] * invc : 0.f;
    w[b * 2048 + l] = v[i] * invZ + sw;
  }
}

// K3: applied[b,d] = sum_l w[b,l]*enc[b,l,d]   (268 MB pass, atomics over 8 l-chunks)
__global__ __launch_bounds__(256) void k_applied(const float* __restrict__ enc,
    const float* __restrict__ w, float* __restrict__ applied){
  int lc = blockIdx.x, b = blockIdx.y, t = threadIdx.x;
  __shared__ float sw[256];
  sw[t] = w[b * 2048 + lc * 256 + t];
  __syncthreads();
  float ax = 0.f, ay = 0.f;
  for (int l = 0; l < 256; ++l){
    const float2 v = *(const float2*)(enc + ((size_t)b * 2048 + lc * 256 + l) * 512 + 2 * t);
    float wl = sw[l];
    ax += wl * v.x; ay += wl * v.y;
  }
  atomicAdd(&applied[b * 512 + 2 * t],     ax);
  atomicAdd(&applied[b * 512 + 2 * t + 1], ay);
}

// K4a: gi[b,o] = x[b,:] . Wih[o,:]  where x = [emb(256) | applied(512)], K=768.
// One wave per (b, 8 consecutive outs); lanes span K (coalesced, L2-resident W).
__global__ __launch_bounds__(256) void k_gi(const float* __restrict__ attn_in,
    const float* __restrict__ applied, const float* __restrict__ Wih, float* __restrict__ gi){
  int wave = threadIdx.x >> 6, lane = threadIdx.x & 63;
  int b = blockIdx.y;
  int o0 = (blockIdx.x * 4 + wave) * 8;
  float a[12];
#pragma unroll
  for (int i = 0; i < 4; ++i)  a[i] = attn_in[b * 512 + lane + i * 64];       // emb
#pragma unroll
  for (int i = 0; i < 8; ++i)  a[4 + i] = applied[b * 512 + lane + i * 64];   // attn+select applied
  float acc[8];
#pragma unroll
  for (int r = 0; r < 8; ++r){
    const float* wrow = Wih + (size_t)(o0 + r) * 768;
    float s = 0.f;
#pragma unroll
    for (int i = 0; i < 12; ++i) s += a[i] * wrow[lane + i * 64];
    acc[r] = s;
  }
#pragma unroll
  for (int m = 1; m < 64; m <<= 1){
#pragma unroll
    for (int r = 0; r < 8; ++r) acc[r] += __shfl_xor(acc[r], m, 64);
  }
  if (lane == 0){
#pragma unroll
    for (int r = 0; r < 8; ++r) gi[(size_t)b * 768 + o0 + r] = acc[r];
  }
}

// K4b: gh[b,o] = pre_state[b,:] . Whh[o,:], K=256.
__global__ __launch_bounds__(256) void k_gh(const float* __restrict__ pre_state,
    const float* __restrict__ Whh, float* __restrict__ gh){
  int wave = threadIdx.x >> 6, lane = threadIdx.x & 63;
  int b = blockIdx.y;
  int o0 = (blockIdx.x * 4 + wave) * 8;
  float a[4];
#pragma unroll
  for (int i = 0; i < 4; ++i) a[i] = pre_state[b * 256 + lane + i * 64];
  float acc[8];
#pragma unroll
  for (int r = 0; r < 8; ++r){
    const float* wrow = Whh + (size_t)(o0 + r) * 256;
    float s = 0.f;
#pragma unroll
    for (int i = 0; i < 4; ++i) s += a[i] * wrow[lane + i * 64];
    acc[r] = s;
  }
#pragma unroll
  for (int m = 1; m < 64; m <<= 1){
#pragma unroll
    for (int r = 0; r < 8; ++r) acc[r] += __shfl_xor(acc[r], m, 64);
  }
  if (lane == 0){
#pragma unroll
    for (int r = 0; r < 8; ++r) gh[(size_t)b * 768 + o0 + r] = acc[r];
  }
}

// K4c: gate combine -> state (fp32 exact, same math as before)
__global__ __launch_bounds__(256) void k_gru2(const float* __restrict__ gi, const float* __restrict__ gh,
    const float* __restrict__ bih, const float* __restrict__ bhh, const float* __restrict__ pre_state,
    float* __restrict__ state, float* __restrict__ out_state){
  int b = blockIdx.x, t = threadIdx.x;
  float ir = gi[(size_t)b * 768 + t]       + bih[t];
  float iz = gi[(size_t)b * 768 + 256 + t] + bih[256 + t];
  float in_= gi[(size_t)b * 768 + 512 + t] + bih[512 + t];
  float hr = gh[(size_t)b * 768 + t]       + bhh[t];
  float hz = gh[(size_t)b * 768 + 256 + t] + bhh[256 + t];
  float hn = gh[(size_t)b * 768 + 512 + t] + bhh[512 + t];
  float r = fast_sigmoid(ir + hr);
  float z = fast_sigmoid(iz + hz);
  float n = fast_tanh(in_ + r * hn);
  float ps = pre_state[b * 256 + t];
  float st = (1.f - z) * n + z * ps;
  state[b * 256 + t] = st;
  out_state[b * 256 + t] = st;
}

// K6: score_g (into out1, temporarily) = state @ Wo + Wo_b, via bf16 MFMA.
__global__ __launch_bounds__(256) void k_scoreg(const float* __restrict__ Wo,
    const float* __restrict__ Wob, const float* __restrict__ state, float* __restrict__ out1){
  int v0 = blockIdx.x * 256;
  int tid = threadIdx.x;
  int wave = tid >> 6, lane = tid & 63;
  int lr = lane & 15, q = lane >> 4;
  __shared__ unsigned short sA[64 * 264];   // state bf16, row stride 264
  __shared__ unsigned short sB[256 * 40];   // WoT slice [n][k'] stride 40
  for (int i = tid; i < 64 * 256; i += 256){
    int r = i >> 8, c = i & 255;
    sA[r * 264 + c] = f2bf(state[i]);
  }
  f32x4 zero = {0.f, 0.f, 0.f, 0.f};
  f32x4 acc[16];
#pragma unroll
  for (int i = 0; i < 16; ++i) acc[i] = zero;
  int v = v0 + tid;
  for (int kk = 0; kk < 8; ++kk){
    __syncthreads();
    for (int r = 0; r < 32; ++r){
      float val = (v < V_) ? Wo[(size_t)(kk * 32 + r) * V_ + v] : 0.f;
      sB[tid * 40 + r] = f2bf(val);
    }
    __syncthreads();
    bf16x8 af = *(const bf16x8*)&sA[(wave * 16 + lr) * 264 + kk * 32 + q * 8];
#pragma unroll
    for (int nf = 0; nf < 16; ++nf){
      bf16x8 bf = *(const bf16x8*)&sB[(nf * 16 + lr) * 40 + q * 8];
      acc[nf] = __builtin_amdgcn_mfma_f32_16x16x32_bf16(af, bf, acc[nf], 0, 0, 0);
    }
  }
#pragma unroll
  for (int nf = 0; nf < 16; ++nf){
    int vv = v0 + nf * 16 + lr;
    if (vv < V_){
      float wb = Wob[vv];
#pragma unroll
      for (int r = 0; r < 4; ++r){
        int bb = wave * 16 + q * 4 + r;
        out1[(size_t)bb * VL + vv] = acc[nf][r] + wb;
      }
    }
  }
}

// K5: score_c[b,l] = sum_h tanh((enc@Wc)[b,l,h] + Wcb[h]) * state[b,h]
__global__ __launch_bounds__(256) void k_scorec(const float* __restrict__ enc,
    const unsigned short* __restrict__ WcT, const float* __restrict__ Wcb,
    const float* __restrict__ state, float* __restrict__ score_c){
  int lt = blockIdx.x, b = blockIdx.y;
  int tid = threadIdx.x;
  int wave = tid >> 6, lane = tid & 63;
  int lr = lane & 15, q = lane >> 4;
  __shared__ unsigned short s_wc[256 * 40];  // [col][k'] stride 40
  __shared__ float s_state[256];
  __shared__ float s_bias[256];
  s_state[tid] = state[b * 256 + tid];
  s_bias[tid]  = Wcb[tid];
  f32x4 zero = {0.f, 0.f, 0.f, 0.f};
  f32x4 acc[16];
#pragma unroll
  for (int i = 0; i < 16; ++i) acc[i] = zero;
  const float* arow = enc + ((size_t)b * 2048 + lt * 64 + wave * 16 + lr) * 512;
  for (int kk = 0; kk < 16; ++kk){
    {
      const uint4* src = (const uint4*)(WcT + (size_t)tid * 512 + kk * 32);
      uint4* dst = (uint4*)&s_wc[tid * 40];
      dst[0] = src[0]; dst[1] = src[1]; dst[2] = src[2]; dst[3] = src[3];
    }
    __syncthreads();
    float4 a0 = *(const float4*)(arow + kk * 32 + q * 8);
    float4 a1 = *(const float4*)(arow + kk * 32 + q * 8 + 4);
    bf16x8 af;
    af[0] = f2bf(a0.x); af[1] = f2bf(a0.y); af[2] = f2bf(a0.z); af[3] = f2bf(a0.w);
    af[4] = f2bf(a1.x); af[5] = f2bf(a1.y); af[6] = f2bf(a1.z); af[7] = f2bf(a1.w);
#pragma unroll
    for (int nf = 0; nf < 16; ++nf){
      bf16x8 bf = *(const bf16x8*)&s_wc[(nf * 16 + lr) * 40 + q * 8];
      acc[nf] = __builtin_amdgcn_mfma_f32_16x16x32_bf16(af, bf, acc[nf], 0, 0, 0);
    }
    __syncthreads();
  }
  float part[4] = {0.f, 0.f, 0.f, 0.f};
#pragma unroll
  for (int nf = 0; nf < 16; ++nf){
    int col = nf * 16 + lr;
    float sv = s_state[col], bv = s_bias[col];
#pragma unroll
    for (int r = 0; r < 4; ++r){
      part[r] += fast_tanh(acc[nf][r] + bv) * sv;
    }
  }
#pragma unroll
  for (int m = 1; m <= 8; m <<= 1){
#pragma unroll
    for (int r = 0; r < 4; ++r) part[r] += __shfl_xor(part[r], m, 64);
  }
  if (lr == 0){
#pragma unroll
    for (int r = 0; r < 4; ++r)
      score_c[b * 2048 + lt * 64 + wave * 16 + q * 4 + r] = part[r];
  }
}

// K7a: per-(b,chunk) online softmax partials over [score_g | score_c]
__global__ __launch_bounds__(256) void k_stats1(const float* __restrict__ out1,
    const float* __restrict__ score_c, float* __restrict__ part){
  int c = blockIdx.x, b = blockIdx.y, t = threadIdx.x;
  int i0 = c * 3328, i1 = i0 + 3328; if (i1 > VL) i1 = VL;
  float m = -3.0e38f, s = 0.f;
  for (int i = i0 + t; i < i1; i += 256){
    float v = (i < V_) ? out1[(size_t)b * VL + i] : score_c[b * 2048 + (i - V_)];
    if (v > m){ s = s * __expf(m - v) + 1.f; m = v; }
    else s += __expf(v - m);
  }
  __shared__ float ms[256], ss[256];
  ms[t] = m; ss[t] = s; __syncthreads();
  for (int o = 128; o; o >>= 1){
    if (t < o){
      float m2 = ms[t + o], s2 = ss[t + o];
      float mn = fmaxf(ms[t], m2);
      ss[t] = ss[t] * __expf(ms[t] - mn) + s2 * __expf(m2 - mn);
      ms[t] = mn;
    }
    __syncthreads();
  }
  if (t == 0){ part[(b * 16 + c) * 2] = ms[0]; part[(b * 16 + c) * 2 + 1] = ss[0]; }
}

// K7b: merge 16 partials per b -> mz
__global__ __launch_bounds__(64) void k_stats2(const float* __restrict__ part, float* __restrict__ mz){
  int b = blockIdx.x, t = threadIdx.x;
  float m = -3.0e38f, s = 0.f;
  if (t < 16){ m = part[(b * 16 + t) * 2]; s = part[(b * 16 + t) * 2 + 1]; }
  for (int o = 1; o < 64; o <<= 1){
    float m2 = __shfl_xor(m, o, 64), s2 = __shfl_xor(s, o, 64);
    float mn = fmaxf(m, m2);
    s = s * __expf(m - mn) + s2 * __expf(m2 - mn);
    m = mn;
  }
  if (t == 0){ mz[2 * b] = m; mz[2 * b + 1] = s; }
}

// K8a: in-place out1[b,i] = i<V ? exp(sg-m)/Z : 0
__global__ __launch_bounds__(256) void k_probg(float* __restrict__ out1, const float* __restrict__ mz){
  int b = blockIdx.y;
  int i = blockIdx.x * 256 + threadIdx.x;
  if (i >= VL) return;
  float m = mz[2 * b], z = mz[2 * b + 1];
  float* row = out1 + (size_t)b * VL;
  row[i] = (i < V_) ? __expf(row[i] - m) / z : 0.f;
}

// K8b: prob_c out + scatter-add into out1 first-V columns
__global__ __launch_bounds__(256) void k_probc(const float* __restrict__ score_c,
    const float* __restrict__ mz, const int* __restrict__ seq,
    float* __restrict__ out1, float* __restrict__ out3){
  int b = blockIdx.y;
  int l = blockIdx.x * 256 + threadIdx.x;
  float m = mz[2 * b], z = mz[2 * b + 1];
  float p = __expf(score_c[b * 2048 + l] - m) / z;
  out3[b * 2048 + l] = p;
  atomicAdd(&out1[(size_t)b * VL + seq[b * 2048 + l]], p);
}

extern "C" void kernel_launch(void* const* d_in, const int* in_sizes, int n_in,
                              void* d_out, int out_size, void* d_ws, size_t ws_size,
                              hipStream_t stream) {
  const int*   idx      = (const int*)d_in[0];
  const float* enc      = (const float*)d_in[1];
  const int*   seq      = (const int*)d_in[2];
  const float* prestate = (const float*)d_in[3];
  const float* ppc      = (const float*)d_in[4];
  const float* embed    = (const float*)d_in[5];
  const float* attn_W   = (const float*)d_in[6];
  const float* attn_b   = (const float*)d_in[7];
  const float* Wih      = (const float*)d_in[8];
  const float* Whh      = (const float*)d_in[9];
  const float* bih      = (const float*)d_in[10];
  const float* bhh      = (const float*)d_in[11];
  const float* Wc       = (const float*)d_in[12];
  const float* Wcb      = (const float*)d_in[13];
  const float* Wo       = (const float*)d_in[14];
  const float* Wob      = (const float*)d_in[15];

  float* out1 = (float*)d_out;                       // (B, V+L)
  float* out2 = out1 + (size_t)B_ * VL;              // state (B,H)
  float* out3 = out2 + (size_t)B_ * H_;              // prob_c (B,L)

  char* w8 = (char*)d_ws;
  unsigned short* WcT = (unsigned short*)(w8 + 0);        // 262144 B
  float* attn_in = (float*)(w8 + 262144);                  // 131072 B
  float* logits  = (float*)(w8 + 393216);                  // 524288 B
  float* wgt     = (float*)(w8 + 917504);                  // 524288 B
  float* applied = (float*)(w8 + 1441792);                 // 131072 B
  float* state   = (float*)(w8 + 1572864);                 // 65536 B
  float* score_c = (float*)(w8 + 1638400);                 // 524288 B
  float* mz      = (float*)(w8 + 2162688);                 // 512 B
  float* cnt     = (float*)(w8 + 2163200);                 // 256 B
  float* gi      = (float*)(w8 + 2163456);                 // 196608 B
  float* gh      = (float*)(w8 + 2360064);                 // 196608 B
  float* part    = (float*)(w8 + 2556672);                 // 8192 B

  k_prep   <<<512, 256, 0, stream>>>(Wc, WcT);
  k_setup  <<<64, 256, 0, stream>>>(idx, seq, embed, prestate, attn_in, applied, cnt);
  k_logits <<<dim3(8, 64), 256, 0, stream>>>(attn_in, attn_W, attn_b, logits);
  k_weights<<<64, 256, 0, stream>>>(logits, seq, idx, ppc, cnt, wgt);
  k_applied<<<dim3(8, 64), 256, 0, stream>>>(enc, wgt, applied);
  k_gi     <<<dim3(24, 64), 256, 0, stream>>>(attn_in, applied, Wih, gi);
  k_gh     <<<dim3(24, 64), 256, 0, stream>>>(prestate, Whh, gh);
  k_gru2   <<<64, 256, 0, stream>>>(gi, gh, bih, bhh, prestate, state, out2);
  k_scoreg <<<197, 256, 0, stream>>>(Wo, Wob, state, out1);
  k_scorec <<<dim3(32, 64), 256, 0, stream>>>(enc, WcT, Wcb, state, score_c);
  k_stats1 <<<dim3(16, 64), 256, 0, stream>>>(out1, score_c, part);
  k_stats2 <<<64, 64, 0, stream>>>(part, mz);
  k_probg  <<<dim3(205, 64), 256, 0, stream>>>(out1, mz);
  k_probc  <<<dim3(8, 64), 256, 0, stream>>>(score_c, mz, seq, out1, out3);
}

// Round 5
// 641.549 us; speedup vs baseline: 1.4766x; 1.1461x over previous
//
#include <hip/hip_runtime.h>

#define B_   64
#define L_   2048
#define H_   256
#define E_   256
#define V_   50257
#define TWOH 512
#define VL   52305   // V_ + L_

typedef short bf16x8 __attribute__((ext_vector_type(8)));
typedef float f32x4  __attribute__((ext_vector_type(4)));

__device__ inline unsigned short f2bf(float f){
  unsigned u = __float_as_uint(f);
  unsigned r = (u + 0x7fffu + ((u >> 16) & 1u)) >> 16;  // RNE
  return (unsigned short)r;
}
__device__ inline float bf2f(unsigned short h){
  return __uint_as_float(((unsigned)h) << 16);
}
__device__ inline float fast_tanh(float x){
  x = fminf(15.f, fmaxf(-15.f, x));
  float e = __expf(2.f * x);
  return (e - 1.f) / (e + 1.f);
}
__device__ inline float fast_sigmoid(float x){
  return 1.f / (1.f + __expf(-x));
}

// K1: WcT prep (rows 4b..4b+4) + attn_in + cnt
__global__ __launch_bounds__(256) void k_prep_setup(const float* __restrict__ Wc,
    unsigned short* __restrict__ WcT, const int* __restrict__ idx, const int* __restrict__ seq,
    const float* __restrict__ embed, const float* __restrict__ pre_state,
    float* __restrict__ attn_in, float* __restrict__ cnt){
  int b = blockIdx.x, t = threadIdx.x;
#pragma unroll
  for (int j = 0; j < 8; ++j){
    int i = b * 2048 + t * 8 + j;
    int n = i >> 9, k = i & 511;
    WcT[i] = f2bf(Wc[(size_t)k * 256 + n]);
  }
  int id = idx[b];
  attn_in[b * 512 + t]       = embed[(size_t)id * 256 + t];
  attn_in[b * 512 + 256 + t] = pre_state[b * 256 + t];
  int c = 0;
  for (int l = t; l < 2048; l += 256) c += (seq[b * 2048 + l] == id) ? 1 : 0;
  __shared__ int red[256];
  red[t] = c; __syncthreads();
  for (int o = 128; o; o >>= 1){ if (t < o) red[t] += red[t + o]; __syncthreads(); }
  if (t == 0) cnt[b] = (float)red[0];
}

// K2: logits[b,l] = attn_in[b,:] . attn_W[:,l] + attn_b[l]
__global__ __launch_bounds__(256) void k_logits(const float* __restrict__ attn_in,
    const float* __restrict__ attn_W, const float* __restrict__ attn_b, float* __restrict__ logits){
  int lt = blockIdx.x, b = blockIdx.y, t = threadIdx.x;
  int l = lt * 256 + t;
  __shared__ float ai[512];
  ai[t] = attn_in[b * 512 + t];
  ai[256 + t] = attn_in[b * 512 + 256 + t];
  __syncthreads();
  float acc = attn_b[l];
  for (int k4 = 0; k4 < 128; ++k4){
    const float4 a = *(const float4*)&ai[k4 * 4];
    acc += a.x * attn_W[(size_t)(k4 * 4 + 0) * 2048 + l]
         + a.y * attn_W[(size_t)(k4 * 4 + 1) * 2048 + l]
         + a.z * attn_W[(size_t)(k4 * 4 + 2) * 2048 + l]
         + a.w * attn_W[(size_t)(k4 * 4 + 3) * 2048 + l];
  }
  logits[b * 2048 + l] = acc;
}

// K3: w[b,l] = softmax_l(logits) + match/max(cnt,1)*pre_prob_c
__global__ __launch_bounds__(256) void k_weights(const float* __restrict__ logits,
    const int* __restrict__ seq, const int* __restrict__ idx, const float* __restrict__ ppc,
    const float* __restrict__ cnt, float* __restrict__ w){
  int b = blockIdx.x, t = threadIdx.x;
  float v[8];
  float m = -3e38f;
#pragma unroll
  for (int i = 0; i < 8; ++i){ v[i] = logits[b * 2048 + i * 256 + t]; m = fmaxf(m, v[i]); }
  __shared__ float red[256];
  red[t] = m; __syncthreads();
  for (int o = 128; o; o >>= 1){ if (t < o) red[t] = fmaxf(red[t], red[t + o]); __syncthreads(); }
  m = red[0]; __syncthreads();
  float s = 0.f;
#pragma unroll
  for (int i = 0; i < 8; ++i){ v[i] = __expf(v[i] - m); s += v[i]; }
  red[t] = s; __syncthreads();
  for (int o = 128; o; o >>= 1){ if (t < o) red[t] += red[t + o]; __syncthreads(); }
  float invZ = 1.f / red[0];
  int id = idx[b];
  float invc = 1.f / fmaxf(cnt[b], 1.f);
#pragma unroll
  for (int i = 0; i < 8; ++i){
    int l = i * 256 + t;
    float sw = (seq[b * 2048 + l] == id) ? ppc[b * 2048 + l] * invc : 0.f;
    w[b * 2048 + l] = v[i] * invZ + sw;
  }
}

// K4: single enc pass: T[b,l,h]=bf16(tanh(enc@Wc+b)) via MFMA, AND per-block
// w-weighted row-sum partials for `applied` (deterministic, no global atomics).
__global__ __launch_bounds__(256) void k_encT(const float* __restrict__ enc,
    const unsigned short* __restrict__ WcT, const float* __restrict__ Wcb,
    const float* __restrict__ w, unsigned short* __restrict__ T, float* __restrict__ part_applied){
  int lt = blockIdx.x, b = blockIdx.y;
  int tid = threadIdx.x;
  int wave = tid >> 6, lane = tid & 63;
  int lr = lane & 15, q = lane >> 4;
  __shared__ unsigned short s_wc[256 * 40];  // [col][k'] stride 40
  __shared__ float s_bias[256];
  __shared__ float s_w[64];
  __shared__ float s_app[512];
  s_bias[tid] = Wcb[tid];
  if (tid < 64) s_w[tid] = w[b * 2048 + lt * 64 + tid];
  s_app[tid] = 0.f; s_app[256 + tid] = 0.f;
  f32x4 zero = {0.f, 0.f, 0.f, 0.f};
  f32x4 acc[16];
#pragma unroll
  for (int i = 0; i < 16; ++i) acc[i] = zero;
  const float* arow = enc + ((size_t)b * 2048 + lt * 64 + wave * 16 + lr) * 512;
  for (int kk = 0; kk < 16; ++kk){
    {
      const uint4* src = (const uint4*)(WcT + (size_t)tid * 512 + kk * 32);
      uint4* dst = (uint4*)&s_wc[tid * 40];
      dst[0] = src[0]; dst[1] = src[1]; dst[2] = src[2]; dst[3] = src[3];
    }
    __syncthreads();
    float4 a0 = *(const float4*)(arow + kk * 32 + q * 8);
    float4 a1 = *(const float4*)(arow + kk * 32 + q * 8 + 4);
    // weighted partial for applied (fp32-exact operands)
    float wrow = s_w[wave * 16 + lr];
    float p[8] = {a0.x*wrow, a0.y*wrow, a0.z*wrow, a0.w*wrow,
                  a1.x*wrow, a1.y*wrow, a1.z*wrow, a1.w*wrow};
#pragma unroll
    for (int m = 1; m <= 8; m <<= 1){
#pragma unroll
      for (int j = 0; j < 8; ++j) p[j] += __shfl_xor(p[j], m, 64);
    }
    if (lr == 0){
#pragma unroll
      for (int j = 0; j < 8; ++j) atomicAdd(&s_app[kk * 32 + q * 8 + j], p[j]);
    }
    bf16x8 af;
    af[0] = f2bf(a0.x); af[1] = f2bf(a0.y); af[2] = f2bf(a0.z); af[3] = f2bf(a0.w);
    af[4] = f2bf(a1.x); af[5] = f2bf(a1.y); af[6] = f2bf(a1.z); af[7] = f2bf(a1.w);
#pragma unroll
    for (int nf = 0; nf < 16; ++nf){
      bf16x8 bf = *(const bf16x8*)&s_wc[(nf * 16 + lr) * 40 + q * 8];
      acc[nf] = __builtin_amdgcn_mfma_f32_16x16x32_bf16(af, bf, acc[nf], 0, 0, 0);
    }
    __syncthreads();
  }
  // epilogue: tanh -> T (D-frag layout: col=lr, row=q*4+r within wave tile)
#pragma unroll
  for (int nf = 0; nf < 16; ++nf){
    int col = nf * 16 + lr;
    float bv = s_bias[col];
#pragma unroll
    for (int r = 0; r < 4; ++r){
      int row = lt * 64 + wave * 16 + q * 4 + r;
      T[((size_t)b * 2048 + row) * 256 + col] = f2bf(fast_tanh(acc[nf][r] + bv));
    }
  }
  part_applied[((size_t)b * 32 + lt) * 512 + tid]       = s_app[tid];
  part_applied[((size_t)b * 32 + lt) * 512 + 256 + tid] = s_app[256 + tid];
}

// K5: applied[b,d] = sum_lt part_applied
__global__ __launch_bounds__(256) void k_appred(const float* __restrict__ part_applied,
    float* __restrict__ applied){
  int b = blockIdx.x, t = threadIdx.x;
  float a0 = 0.f, a1 = 0.f;
  for (int lt = 0; lt < 32; ++lt){
    a0 += part_applied[((size_t)b * 32 + lt) * 512 + t];
    a1 += part_applied[((size_t)b * 32 + lt) * 512 + 256 + t];
  }
  applied[b * 512 + t] = a0;
  applied[b * 512 + 256 + t] = a1;
}

// K6: gi (bx<24) / gh (bx>=24) GEMV, one wave per 8 outs, lanes span K.
__global__ __launch_bounds__(256) void k_giGh(const float* __restrict__ attn_in,
    const float* __restrict__ applied, const float* __restrict__ pre_state,
    const float* __restrict__ Wih, const float* __restrict__ Whh,
    float* __restrict__ gi, float* __restrict__ gh){
  int wave = threadIdx.x >> 6, lane = threadIdx.x & 63;
  int b = blockIdx.y;
  if (blockIdx.x < 24){
    int o0 = (blockIdx.x * 4 + wave) * 8;
    float a[12];
#pragma unroll
    for (int i = 0; i < 4; ++i)  a[i] = attn_in[b * 512 + lane + i * 64];
#pragma unroll
    for (int i = 0; i < 8; ++i)  a[4 + i] = applied[b * 512 + lane + i * 64];
    float acc[8];
#pragma unroll
    for (int r = 0; r < 8; ++r){
      const float* wrow = Wih + (size_t)(o0 + r) * 768;
      float s = 0.f;
#pragma unroll
      for (int i = 0; i < 12; ++i) s += a[i] * wrow[lane + i * 64];
      acc[r] = s;
    }
#pragma unroll
    for (int m = 1; m < 64; m <<= 1){
#pragma unroll
      for (int r = 0; r < 8; ++r) acc[r] += __shfl_xor(acc[r], m, 64);
    }
    if (lane == 0){
#pragma unroll
      for (int r = 0; r < 8; ++r) gi[(size_t)b * 768 + o0 + r] = acc[r];
    }
  } else {
    int o0 = ((blockIdx.x - 24) * 4 + wave) * 8;
    float a[4];
#pragma unroll
    for (int i = 0; i < 4; ++i) a[i] = pre_state[b * 256 + lane + i * 64];
    float acc[8];
#pragma unroll
    for (int r = 0; r < 8; ++r){
      const float* wrow = Whh + (size_t)(o0 + r) * 256;
      float s = 0.f;
#pragma unroll
      for (int i = 0; i < 4; ++i) s += a[i] * wrow[lane + i * 64];
      acc[r] = s;
    }
#pragma unroll
    for (int m = 1; m < 64; m <<= 1){
#pragma unroll
      for (int r = 0; r < 8; ++r) acc[r] += __shfl_xor(acc[r], m, 64);
    }
    if (lane == 0){
#pragma unroll
      for (int r = 0; r < 8; ++r) gh[(size_t)b * 768 + o0 + r] = acc[r];
    }
  }
}

// K7: gate combine -> state
__global__ __launch_bounds__(256) void k_gru2(const float* __restrict__ gi, const float* __restrict__ gh,
    const float* __restrict__ bih, const float* __restrict__ bhh, const float* __restrict__ pre_state,
    float* __restrict__ state, float* __restrict__ out_state){
  int b = blockIdx.x, t = threadIdx.x;
  float ir = gi[(size_t)b * 768 + t]       + bih[t];
  float iz = gi[(size_t)b * 768 + 256 + t] + bih[256 + t];
  float in_= gi[(size_t)b * 768 + 512 + t] + bih[512 + t];
  float hr = gh[(size_t)b * 768 + t]       + bhh[t];
  float hz = gh[(size_t)b * 768 + 256 + t] + bhh[256 + t];
  float hn = gh[(size_t)b * 768 + 512 + t] + bhh[512 + t];
  float r = fast_sigmoid(ir + hr);
  float z = fast_sigmoid(iz + hz);
  float n = fast_tanh(in_ + r * hn);
  float ps = pre_state[b * 256 + t];
  float st = (1.f - z) * n + z * ps;
  state[b * 256 + t] = st;
  out_state[b * 256 + t] = st;
}

// K8: score_g = state @ Wo + Wo_b (bf16 MFMA), 64-wide v-tiles, 786 blocks.
__global__ __launch_bounds__(256) void k_scoreg(const float* __restrict__ Wo,
    const float* __restrict__ Wob, const float* __restrict__ state, float* __restrict__ out1){
  int v0 = blockIdx.x * 64;
  int tid = threadIdx.x;
  int wave = tid >> 6, lane = tid & 63;
  int lr = lane & 15, q = lane >> 4;
  __shared__ unsigned short sA[64 * 264];   // state bf16 [b][k]
  __shared__ unsigned short sB[64 * 40];    // Wo slice [v][k'] stride 40
  for (int i = tid; i < 64 * 256; i += 256){
    int r = i >> 8, c = i & 255;
    sA[r * 264 + c] = f2bf(state[i]);
  }
  f32x4 zero = {0.f, 0.f, 0.f, 0.f};
  f32x4 acc[4];
#pragma unroll
  for (int i = 0; i < 4; ++i) acc[i] = zero;
  int c = tid & 63, rg = tid >> 6;   // col, k-row group
  int v = v0 + c;
  for (int kk = 0; kk < 8; ++kk){
    __syncthreads();
#pragma unroll
    for (int j = 0; j < 8; ++j){
      float val = (v < V_) ? Wo[(size_t)(kk * 32 + rg * 8 + j) * V_ + v] : 0.f;
      sB[c * 40 + rg * 8 + j] = f2bf(val);
    }
    __syncthreads();
    bf16x8 af = *(const bf16x8*)&sA[(wave * 16 + lr) * 264 + kk * 32 + q * 8];
#pragma unroll
    for (int nf = 0; nf < 4; ++nf){
      bf16x8 bf = *(const bf16x8*)&sB[(nf * 16 + lr) * 40 + q * 8];
      acc[nf] = __builtin_amdgcn_mfma_f32_16x16x32_bf16(af, bf, acc[nf], 0, 0, 0);
    }
  }
#pragma unroll
  for (int nf = 0; nf < 4; ++nf){
    int vv = v0 + nf * 16 + lr;
    if (vv < V_){
      float wb = Wob[vv];
#pragma unroll
      for (int r = 0; r < 4; ++r){
        int bb = wave * 16 + q * 4 + r;
        out1[(size_t)bb * VL + vv] = acc[nf][r] + wb;
      }
    }
  }
}

// K9: score_c[b,l] = sum_h T[b,l,h] * state[b,h]
__global__ __launch_bounds__(256) void k_scorec2(const unsigned short* __restrict__ T,
    const float* __restrict__ state, float* __restrict__ score_c){
  int lt = blockIdx.x, b = blockIdx.y;
  int tid = threadIdx.x;
  int g = tid >> 5, hl = tid & 31;
  float st[8];
  {
    float4 s0 = *(const float4*)&state[b * 256 + hl * 8];
    float4 s1 = *(const float4*)&state[b * 256 + hl * 8 + 4];
    st[0]=s0.x; st[1]=s0.y; st[2]=s0.z; st[3]=s0.w;
    st[4]=s1.x; st[5]=s1.y; st[6]=s1.z; st[7]=s1.w;
  }
#pragma unroll
  for (int it = 0; it < 8; ++it){
    int row = lt * 64 + g * 8 + it;
    bf16x8 tv = *(const bf16x8*)&T[((size_t)b * 2048 + row) * 256 + hl * 8];
    float acc = 0.f;
#pragma unroll
    for (int j = 0; j < 8; ++j) acc += bf2f((unsigned short)tv[j]) * st[j];
#pragma unroll
    for (int m = 1; m <= 16; m <<= 1) acc += __shfl_xor(acc, m, 64);
    if (hl == 0) score_c[b * 2048 + row] = acc;
  }
}

// K10a: per-(b,chunk) online softmax partials over [score_g | score_c]
__global__ __launch_bounds__(256) void k_stats1(const float* __restrict__ out1,
    const float* __restrict__ score_c, float* __restrict__ part){
  int c = blockIdx.x, b = blockIdx.y, t = threadIdx.x;
  int i0 = c * 3328, i1 = i0 + 3328; if (i1 > VL) i1 = VL;
  float m = -3.0e38f, s = 0.f;
  for (int i = i0 + t; i < i1; i += 256){
    float v = (i < V_) ? out1[(size_t)b * VL + i] : score_c[b * 2048 + (i - V_)];
    if (v > m){ s = s * __expf(m - v) + 1.f; m = v; }
    else s += __expf(v - m);
  }
  __shared__ float ms[256], ss[256];
  ms[t] = m; ss[t] = s; __syncthreads();
  for (int o = 128; o; o >>= 1){
    if (t < o){
      float m2 = ms[t + o], s2 = ss[t + o];
      float mn = fmaxf(ms[t], m2);
      ss[t] = ss[t] * __expf(ms[t] - mn) + s2 * __expf(m2 - mn);
      ms[t] = mn;
    }
    __syncthreads();
  }
  if (t == 0){ part[(b * 16 + c) * 2] = ms[0]; part[(b * 16 + c) * 2 + 1] = ss[0]; }
}

// K10b: merge 16 partials per b -> mz
__global__ __launch_bounds__(64) void k_stats2(const float* __restrict__ part, float* __restrict__ mz){
  int b = blockIdx.x, t = threadIdx.x;
  float m = -3.0e38f, s = 0.f;
  if (t < 16){ m = part[(b * 16 + t) * 2]; s = part[(b * 16 + t) * 2 + 1]; }
  for (int o = 1; o < 64; o <<= 1){
    float m2 = __shfl_xor(m, o, 64), s2 = __shfl_xor(s, o, 64);
    float mn = fmaxf(m, m2);
    s = s * __expf(m - mn) + s2 * __expf(m2 - mn);
    m = mn;
  }
  if (t == 0){ mz[2 * b] = m; mz[2 * b + 1] = s; }
}

// K11: in-place out1[b,i] = i<V ? exp(sg-m)/Z : 0
__global__ __launch_bounds__(256) void k_probg(float* __restrict__ out1, const float* __restrict__ mz){
  int b = blockIdx.y;
  int i = blockIdx.x * 256 + threadIdx.x;
  if (i >= VL) return;
  float m = mz[2 * b], z = mz[2 * b + 1];
  float* row = out1 + (size_t)b * VL;
  row[i] = (i < V_) ? __expf(row[i] - m) / z : 0.f;
}

// K12: prob_c out + scatter-add into out1 first-V columns
__global__ __launch_bounds__(256) void k_probc(const float* __restrict__ score_c,
    const float* __restrict__ mz, const int* __restrict__ seq,
    float* __restrict__ out1, float* __restrict__ out3){
  int b = blockIdx.y;
  int l = blockIdx.x * 256 + threadIdx.x;
  float m = mz[2 * b], z = mz[2 * b + 1];
  float p = __expf(score_c[b * 2048 + l] - m) / z;
  out3[b * 2048 + l] = p;
  atomicAdd(&out1[(size_t)b * VL + seq[b * 2048 + l]], p);
}

extern "C" void kernel_launch(void* const* d_in, const int* in_sizes, int n_in,
                              void* d_out, int out_size, void* d_ws, size_t ws_size,
                              hipStream_t stream) {
  const int*   idx      = (const int*)d_in[0];
  const float* enc      = (const float*)d_in[1];
  const int*   seq      = (const int*)d_in[2];
  const float* prestate = (const float*)d_in[3];
  const float* ppc      = (const float*)d_in[4];
  const float* embed    = (const float*)d_in[5];
  const float* attn_W   = (const float*)d_in[6];
  const float* attn_b   = (const float*)d_in[7];
  const float* Wih      = (const float*)d_in[8];
  const float* Whh      = (const float*)d_in[9];
  const float* bih      = (const float*)d_in[10];
  const float* bhh      = (const float*)d_in[11];
  const float* Wc       = (const float*)d_in[12];
  const float* Wcb      = (const float*)d_in[13];
  const float* Wo       = (const float*)d_in[14];
  const float* Wob      = (const float*)d_in[15];

  float* out1 = (float*)d_out;                       // (B, V+L)
  float* out2 = out1 + (size_t)B_ * VL;              // state (B,H)
  float* out3 = out2 + (size_t)B_ * H_;              // prob_c (B,L)

  char* w8 = (char*)d_ws;
  unsigned short* WcT = (unsigned short*)(w8 + 0);         // 262144 B
  float* attn_in = (float*)(w8 + 262144);                  // 131072 B
  float* logits  = (float*)(w8 + 393216);                  // 524288 B
  float* wgt     = (float*)(w8 + 917504);                  // 524288 B
  float* applied = (float*)(w8 + 1441792);                 // 131072 B
  float* state   = (float*)(w8 + 1572864);                 // 65536 B
  float* score_c = (float*)(w8 + 1638400);                 // 524288 B
  float* mz      = (float*)(w8 + 2162688);                 // 512 B
  float* cnt     = (float*)(w8 + 2163200);                 // 256 B
  float* gi      = (float*)(w8 + 2163456);                 // 196608 B
  float* gh      = (float*)(w8 + 2360064);                 // 196608 B
  float* part    = (float*)(w8 + 2556672);                 // 8192 B
  float* part_app= (float*)(w8 + 2564864);                 // 4194304 B
  unsigned short* T = (unsigned short*)(w8 + 8388608);     // 67108864 B

  k_prep_setup<<<64, 256, 0, stream>>>(Wc, WcT, idx, seq, embed, prestate, attn_in, cnt);
  k_logits <<<dim3(8, 64), 256, 0, stream>>>(attn_in, attn_W, attn_b, logits);
  k_weights<<<64, 256, 0, stream>>>(logits, seq, idx, ppc, cnt, wgt);
  k_encT   <<<dim3(32, 64), 256, 0, stream>>>(enc, WcT, Wcb, wgt, T, part_app);
  k_appred <<<64, 256, 0, stream>>>(part_app, applied);
  k_giGh   <<<dim3(48, 64), 256, 0, stream>>>(attn_in, applied, prestate, Wih, Whh, gi, gh);
  k_gru2   <<<64, 256, 0, stream>>>(gi, gh, bih, bhh, prestate, state, out2);
  k_scoreg <<<786, 256, 0, stream>>>(Wo, Wob, state, out1);
  k_scorec2<<<dim3(32, 64), 256, 0, stream>>>(T, state, score_c);
  k_stats1 <<<dim3(16, 64), 256, 0, stream>>>(out1, score_c, part);
  k_stats2 <<<64, 64, 0, stream>>>(part, mz);
  k_probg  <<<dim3(205, 64), 256, 0, stream>>>(out1, mz);
  k_probc  <<<dim3(8, 64), 256, 0, stream>>>(score_c, mz, seq, out1, out3);
}